// Round 1
// baseline (17575.772 us; speedup 1.0000x reference)
//
#include <hip/hip_runtime.h>
#include <cstddef>
#include <cstdint>

// RowLSTM: B=32, C=3, H=W=64, HC=128, L=7, K=3 (causal along W), NC=256.
// Recurrence: 64 rows x 7 layers, each step = conv1d(cur,Wx)+bx+conv1d(h,Wh),
// LSTM gates, h/c update. Output proj per row to (B,768,H,W) fp32.

#define B_SZ  32
#define HC    128
#define WIMG  64
#define NL    7
#define LDSS  68            // LDS row stride (floats): 4 halo + 64 data, 16B-aligned rows
#define ROW   (HC * WIMG)   // 8192 floats per (layer,parity,batch) state row

__device__ __forceinline__ float sigmf(float v) {
    return 1.0f / (1.0f + __expf(-v));
}
__device__ __forceinline__ float tanh_fast(float v) {
    v = fminf(fmaxf(v, -15.0f), 15.0f);
    float e = __expf(2.0f * v);
    return (e - 1.0f) / (e + 1.0f);
}

// One (h, l) step. Grid: 512 blocks = 32 batches x 16 d-slices (8 hidden ch each).
// Each block computes comb rows {g*128 + j*8 + d : g=0..3, d=0..7} x all 64 w,
// then the LSTM gate update for its 8 hidden channels.
__global__ __launch_bounds__(256, 2) void lstm_step(
    const int* __restrict__ x, const float* __restrict__ Win, const float* __restrict__ bin,
    const float* __restrict__ Wx, const float* __restrict__ bx, const float* __restrict__ Wh,
    float* __restrict__ hbuf, float* __restrict__ cbuf, int l, int h)
{
    __shared__ float curS[HC * LDSS];
    __shared__ float hsS [HC * LDSS];
    __shared__ int   xS[3 * WIMG];

    const int t  = threadIdx.x;
    const int b  = blockIdx.x >> 4;
    const int j  = blockIdx.x & 15;
    const int p  = h & 1;
    const int pp = p ^ 1;

    float*       hw = hbuf + (size_t)((l * 2 + p ) * B_SZ + b) * ROW;
    const float* hr = hbuf + (size_t)((l * 2 + pp) * B_SZ + b) * ROW;
    float*       cw = cbuf + (size_t)((l * 2 + p ) * B_SZ + b) * ROW;
    const float* cr = cbuf + (size_t)((l * 2 + pp) * B_SZ + b) * ROW;

    // ---- stage hidden state (previous row) into LDS ----
    for (int c4 = t; c4 < ROW / 4; c4 += 256) {
        int ic = c4 >> 4, pos = c4 & 15;
        *(float4*)&hsS[ic * LDSS + 4 + pos * 4] = ((const float4*)hr)[c4];
    }
    // ---- stage cur input into LDS (l==0: compute input projection on the fly) ----
    if (l == 0) {
        if (t < 3 * WIMG) xS[t] = x[(size_t)b * 3 * 4096 + (t >> 6) * 4096 + h * 64 + (t & 63)];
        __syncthreads();
        for (int v = t; v < HC * WIMG; v += 256) {
            int ic = v >> 6, w = v & 63;
            float a = bin[ic] + (Win[ic * 3 + 0] * (float)xS[w]
                               + Win[ic * 3 + 1] * (float)xS[64 + w]
                               + Win[ic * 3 + 2] * (float)xS[128 + w]) * (1.0f / 255.0f);
            curS[ic * LDSS + 4 + w] = a;
        }
    } else {
        const float* cu = hbuf + (size_t)(((l - 1) * 2 + p) * B_SZ + b) * ROW;
        for (int c4 = t; c4 < ROW / 4; c4 += 256) {
            int ic = c4 >> 4, pos = c4 & 15;
            *(float4*)&curS[ic * LDSS + 4 + pos * 4] = ((const float4*)cu)[c4];
        }
    }
    // zero halo columns [0..3] (causal left-pad; reads touch [2..3])
    if (t < HC) {
        *(float4*)&curS[t * LDSS] = float4{0.f, 0.f, 0.f, 0.f};
        *(float4*)&hsS [t * LDSS] = float4{0.f, 0.f, 0.f, 0.f};
    }
    __syncthreads();

    // ---- causal conv: each thread 2 oc x 4 w, K = 128 ic x 3 taps x 2 sources ----
    const int ocq = t >> 4;            // 0..15
    const int w0  = (t & 15) << 2;     // 0,4,...,60
    int oc[2];
    const float *pwx[2], *pwh[2];
    #pragma unroll
    for (int e = 0; e < 2; e++) {
        int ocl  = ocq * 2 + e;        // 0..31
        int gate = ocl >> 3, dloc = ocl & 7;
        oc[e] = gate * HC + j * 8 + dloc;               // 0..511
        pwx[e] = Wx + ((size_t)l * 512 + oc[e]) * (HC * 3);
        pwh[e] = Wh + ((size_t)l * 512 + oc[e]) * (HC * 3);
    }
    float acc[2][4] = {{0.f,0.f,0.f,0.f},{0.f,0.f,0.f,0.f}};
    for (int ic = 0; ic < HC; ic++) {
        float cu[6], hh[6];
        #pragma unroll
        for (int k = 0; k < 6; k++) {
            cu[k] = curS[ic * LDSS + 2 + w0 + k];
            hh[k] = hsS [ic * LDSS + 2 + w0 + k];
        }
        #pragma unroll
        for (int e = 0; e < 2; e++) {
            float a0 = pwx[e][ic * 3 + 0], a1 = pwx[e][ic * 3 + 1], a2 = pwx[e][ic * 3 + 2];
            float h0 = pwh[e][ic * 3 + 0], h1 = pwh[e][ic * 3 + 1], h2 = pwh[e][ic * 3 + 2];
            #pragma unroll
            for (int ww = 0; ww < 4; ww++)
                acc[e][ww] += a0 * cu[ww] + a1 * cu[ww + 1] + a2 * cu[ww + 2]
                            + h0 * hh[ww] + h1 * hh[ww + 1] + h2 * hh[ww + 2];
        }
    }
    __syncthreads();                     // all curS/hsS reads done
    float* combS = curS;                 // alias comb buffer over curS (32 x 64)
    #pragma unroll
    for (int e = 0; e < 2; e++) {
        float bb  = bx[l * 512 + oc[e]];
        int   ocl = ocq * 2 + e;
        #pragma unroll
        for (int ww = 0; ww < 4; ww++)
            combS[ocl * 64 + w0 + ww] = acc[e][ww] + bb;
    }
    __syncthreads();

    // ---- LSTM gate update for this block's 8 hidden channels ----
    for (int v = t; v < 8 * WIMG; v += 256) {
        int d = v >> 6, w = v & 63;
        float ii = combS[(0 * 8 + d) * 64 + w];
        float ff = combS[(1 * 8 + d) * 64 + w];
        float oo = combS[(2 * 8 + d) * 64 + w];
        float gg = combS[(3 * 8 + d) * 64 + w];
        int   dg = j * 8 + d;
        float cold = cr[dg * 64 + w];
        float nc = sigmf(ff) * cold + sigmf(ii) * tanh_fast(gg);
        float nh = sigmf(oo) * tanh_fast(nc);
        cw[dg * 64 + w] = nc;
        hw[dg * 64 + w] = nh;
    }
}

// Output projection for one row h: logits[b, o, h, w] = b_out[o] + sum_d W_out[o,d]*nh[b,d,w]
// Grid: 384 blocks = 32 batches x 12 oc-slices (64 oc each).
__global__ __launch_bounds__(256, 2) void proj_row(
    const float* __restrict__ Wout, const float* __restrict__ bout,
    const float* __restrict__ hbuf, float* __restrict__ out, int h)
{
    __shared__ float S[HC * WIMG];
    const int t  = threadIdx.x;
    const int b  = blockIdx.x / 12;
    const int jo = blockIdx.x % 12;
    const float* hr = hbuf + (size_t)((6 * 2 + (h & 1)) * B_SZ + b) * ROW;
    for (int c4 = t; c4 < ROW / 4; c4 += 256) ((float4*)S)[c4] = ((const float4*)hr)[c4];
    __syncthreads();

    const int o0 = jo * 64 + (t >> 4) * 4;
    const int w0 = (t & 15) * 4;
    float acc[4][4] = {};
    const float* pw = Wout + (size_t)o0 * HC;
    for (int d = 0; d < HC; d++) {
        float s0 = S[d * 64 + w0 + 0], s1 = S[d * 64 + w0 + 1];
        float s2 = S[d * 64 + w0 + 2], s3 = S[d * 64 + w0 + 3];
        #pragma unroll
        for (int e = 0; e < 4; e++) {
            float wv = pw[e * HC + d];
            acc[e][0] += wv * s0; acc[e][1] += wv * s1;
            acc[e][2] += wv * s2; acc[e][3] += wv * s3;
        }
    }
    #pragma unroll
    for (int e = 0; e < 4; e++) {
        float bb = bout[o0 + e];
        float4 r = { acc[e][0] + bb, acc[e][1] + bb, acc[e][2] + bb, acc[e][3] + bb };
        *(float4*)&out[(((size_t)b * 768 + o0 + e) * 64 + h) * 64 + w0] = r;
    }
}

extern "C" void kernel_launch(void* const* d_in, const int* in_sizes, int n_in,
                              void* d_out, int out_size, void* d_ws, size_t ws_size,
                              hipStream_t stream) {
    const int*   x    = (const int*)  d_in[0];
    const float* Win  = (const float*)d_in[1];
    const float* bin  = (const float*)d_in[2];
    const float* Wx   = (const float*)d_in[3];
    const float* bx   = (const float*)d_in[4];
    const float* Wh   = (const float*)d_in[5];
    const float* Wout = (const float*)d_in[6];
    const float* bout = (const float*)d_in[7];
    float* out = (float*)d_out;

    // workspace: hbuf + cbuf, each [L][2 parity][B][HC][W] fp32 (14.68 MB each)
    float* hbuf = (float*)d_ws;
    float* cbuf = hbuf + (size_t)NL * 2 * B_SZ * ROW;
    size_t state_bytes = (size_t)2 * NL * 2 * B_SZ * ROW * sizeof(float);
    hipMemsetAsync(d_ws, 0, state_bytes, stream);   // zero h0/c0 every call (deterministic)

    for (int h = 0; h < 64; h++) {
        for (int l = 0; l < NL; l++)
            lstm_step<<<dim3(512), dim3(256), 0, stream>>>(x, Win, bin, Wx, bx, Wh,
                                                           hbuf, cbuf, l, h);
        proj_row<<<dim3(384), dim3(256), 0, stream>>>(Wout, bout, hbuf, out, h);
    }
}

// Round 3
// 8084.199 us; speedup vs baseline: 2.1741x; 2.1741x over previous
//
#include <hip/hip_runtime.h>
#include <cstddef>
#include <cstdint>

// RowLSTM on MFMA: B=32, HC=128, L=7, H=W=64, K=3 causal.
// comb[512][64] = Wx*cur + Wh*hs per (h,l,b): im2col GEMM, K=768,
// v_mfma_f32_32x32x16_bf16. Weights split-bf16 (hi+lo, 2 passes);
// states single bf16. ws = 26.97 MB; LDS = ~55 KB.
//
// Layouts:
//  Apk[l][part][j][ot][kc][lane][8]  bf16 (exact A-frag order)
//  hB [l][parity][b][66 rows (2 pad + w)][128 ic]  bf16 (transposed state)
//  cB [l][b][128][64] f32 (in-place update)
//  hf32 [b][128][64] f32 (layer-6 mirror for proj, no parity)

#define NL    7
#define HC    128
#define B_SZ  32
#define WI    64
#define HROW  8448   // 66*128
#define CROW  8192   // 128*64

typedef __attribute__((ext_vector_type(8)))  short short8v;
typedef __attribute__((ext_vector_type(16))) float f32x16;
typedef __attribute__((ext_vector_type(4)))  unsigned int uint4v;

__device__ __forceinline__ unsigned short bf16_rn(float f) {
    unsigned int u = __builtin_bit_cast(unsigned int, f);
    u += 0x7fffu + ((u >> 16) & 1u);
    return (unsigned short)(u >> 16);
}
__device__ __forceinline__ float bf16_to_f(unsigned short s) {
    unsigned int u = ((unsigned int)s) << 16;
    return __builtin_bit_cast(float, u);
}
__device__ __forceinline__ float sigmf(float v) { return 1.0f / (1.0f + __expf(-v)); }
__device__ __forceinline__ float tanh_fast(float v) {
    v = fminf(fmaxf(v, -15.0f), 15.0f);
    float e = __expf(2.0f * v);
    return (e - 1.0f) / (e + 1.0f);
}

// ---- pack Wx/Wh into MFMA A-fragment order, split hi/lo bf16 ----
// tid = ((((l*2+part)*8 + j)*2 + ot)*48 + kc)*64 + lane ; 8 elems per tid.
// A-frag (32x32x16): row m = lane&31, k = (lane>>5)*8 + e (contiguous).
__global__ __launch_bounds__(256) void pack_weights(
    const float* __restrict__ Wx, const float* __restrict__ Wh,
    unsigned short* __restrict__ Apk)
{
    int tid = blockIdx.x * 256 + threadIdx.x;          // 0 .. 688127
    int lane = tid & 63; int tmp = tid >> 6;
    int kc = tmp % 48;   tmp /= 48;
    int ot = tmp & 1;    tmp >>= 1;
    int j  = tmp & 7;    tmp >>= 3;
    int part = tmp & 1;  int l = tmp >> 1;
    int m  = ot * 32 + (lane & 31);                    // comb-local row 0..63
    int oc = (m >> 4) * 128 + j * 16 + (m & 15);       // gate*128 + j*16 + d
    int k0 = kc * 16 + (lane >> 5) * 8;
    unsigned short v8[8];
    #pragma unroll
    for (int e = 0; e < 8; e++) {
        int K = k0 + e;                                // K = src*384 + ktap*128 + ic
        int src = K / 384; int rr = K - src * 384;
        int ktap = rr >> 7; int ic = rr & 127;
        const float* Wp = src ? Wh : Wx;
        float v = Wp[((size_t)(l * 512 + oc) * 128 + ic) * 3 + ktap];
        unsigned short hi = bf16_rn(v);
        v8[e] = part ? bf16_rn(v - bf16_to_f(hi)) : hi;
    }
    *(uint4v*)(Apk + (size_t)tid * 8) = *(const uint4v*)v8;
}

// ---- one (h,l) step: 256 blocks = 8 xcd x 4 b x 8 j (16 hidden ch each) ----
__global__ __launch_bounds__(256, 1) void lstm_step(
    const unsigned short* __restrict__ Apk, const float* __restrict__ bx,
    const int* __restrict__ x, const float* __restrict__ Win, const float* __restrict__ bin,
    unsigned short* __restrict__ hB, float* __restrict__ cB, float* __restrict__ hf32,
    int l, int h)
{
    __shared__ unsigned short Bs[2 * HROW];   // cur, hs (33.8 KB), XOR-swizzled rows
    __shared__ float combS[64 * 64];          // 16 KB
    __shared__ float hS[16 * 64];             // 4 KB
    __shared__ float bxs[64];
    __shared__ float xS[192];

    const int t = threadIdx.x;
    const int xcd = blockIdx.x & 7, q = blockIdx.x >> 3;
    const int b = xcd * 4 + (q & 3), j = q >> 2;
    const int p = h & 1, pp = p ^ 1;

    // ---- stage hs (prev row, this layer) ----
    const unsigned short* hsp = hB + (size_t)((l * 2 + pp) * B_SZ + b) * HROW;
    for (int ch = t; ch < 1056; ch += 256) {
        int wr = ch >> 4, icb = ch & 15;
        uint4v v = *(const uint4v*)(hsp + wr * 128 + icb * 8);
        *(uint4v*)((char*)(Bs + HROW) + wr * 256 + ((icb * 16) ^ ((wr & 7) << 4))) = v;
    }
    // ---- stage cur (prev layer this row, or input projection for l==0) ----
    if (l > 0) {
        const unsigned short* curp = hB + (size_t)(((l - 1) * 2 + p) * B_SZ + b) * HROW;
        for (int ch = t; ch < 1056; ch += 256) {
            int wr = ch >> 4, icb = ch & 15;
            uint4v v = *(const uint4v*)(curp + wr * 128 + icb * 8);
            *(uint4v*)((char*)Bs + wr * 256 + ((icb * 16) ^ ((wr & 7) << 4))) = v;
        }
    } else {
        if (t < 192) xS[t] = (float)x[(size_t)(b * 3 + t / 64) * 4096 + h * 64 + (t & 63)] * (1.0f / 255.0f);
        {   // zero pad rows 0,1 of cur plane (256 elems, one per thread)
            int wr = t >> 7, ic = t & 127;
            *(unsigned short*)((char*)Bs + wr * 256 + (((ic >> 3) * 16) ^ ((wr & 7) << 4)) + (ic & 7) * 2) = 0;
        }
        __syncthreads();
        #pragma unroll 4
        for (int e = 0; e < 32; e++) {
            int idx = e * 256 + t; int w = idx >> 7, ic = idx & 127;
            float v = bin[ic] + Win[ic * 3 + 0] * xS[w]
                              + Win[ic * 3 + 1] * xS[64 + w]
                              + Win[ic * 3 + 2] * xS[128 + w];
            int wr = w + 2;
            *(unsigned short*)((char*)Bs + wr * 256 + (((ic >> 3) * 16) ^ ((wr & 7) << 4)) + (ic & 7) * 2) = bf16_rn(v);
        }
    }
    if (t < 64) bxs[t] = bx[l * 512 + (t >> 4) * 128 + j * 16 + (t & 15)];
    __syncthreads();

    // ---- MFMA: 4 waves = (ot: oc-half) x (wt: w-half), 32x32 tile each ----
    const int lane = t & 63, wave = t >> 6;
    const int ot = wave >> 1, wt = wave & 1;
    const int ln31 = lane & 31, lh = lane >> 5;

    const unsigned short* Ah = Apk + ((((size_t)(l * 2 + 0) * 8 + j) * 2 + ot) * 48) * 512 + lane * 8;
    const unsigned short* Al = Apk + ((((size_t)(l * 2 + 1) * 8 + j) * 2 + ot) * 48) * 512 + lane * 8;

    f32x16 acc;
    #pragma unroll
    for (int r = 0; r < 16; r++) acc[r] = 0.0f;

    #pragma unroll
    for (int kc = 0; kc < 48; kc++) {
        const int src  = kc / 24;
        const int ktap = (kc % 24) >> 3;
        const int icb2 = kc & 7;
        const int wr   = wt * 32 + ln31 + ktap;        // B row = n + ktap (causal)
        const int byoff = (icb2 * 32 + lh * 16) ^ ((wr & 7) << 4);
        short8v ahi = *(const short8v*)(Ah + kc * 512);
        short8v alo = *(const short8v*)(Al + kc * 512);
        short8v bv  = *(const short8v*)((char*)(Bs + (size_t)src * HROW) + wr * 256 + byoff);
        acc = __builtin_amdgcn_mfma_f32_32x32x16_bf16(ahi, bv, acc, 0, 0, 0);
        acc = __builtin_amdgcn_mfma_f32_32x32x16_bf16(alo, bv, acc, 0, 0, 0);
    }

    // C/D layout (verified): col=lane&31, row=(reg&3)+8*(reg>>2)+4*(lane>>5)
    #pragma unroll
    for (int r = 0; r < 16; r++) {
        int row = (r & 3) + 8 * (r >> 2) + 4 * lh;
        combS[(ot * 32 + row) * 64 + wt * 32 + ln31] = acc[r];
    }
    __syncthreads();

    // ---- gates + in-place c update ----
    float* cp = cB + (size_t)(l * B_SZ + b) * CROW;
    #pragma unroll
    for (int e = 0; e < 4; e++) {
        int idx = e * 256 + t; int d = idx >> 6, w = idx & 63;
        float gi = combS[(     d) * 64 + w] + bxs[     d];
        float gf = combS[(16 + d) * 64 + w] + bxs[16 + d];
        float go = combS[(32 + d) * 64 + w] + bxs[32 + d];
        float gg = combS[(48 + d) * 64 + w] + bxs[48 + d];
        float cold = cp[(j * 16 + d) * 64 + w];
        float nc = sigmf(gf) * cold + sigmf(gi) * tanh_fast(gg);
        float nh = sigmf(go) * tanh_fast(nc);
        cp[(j * 16 + d) * 64 + w] = nc;
        hS[d * 64 + w] = nh;
        if (l == 6) hf32[(size_t)b * CROW + (j * 16 + d) * 64 + w] = nh;
    }
    __syncthreads();

    // ---- transposed bf16 h-state write: row w+2, ic = j*16 + 0..15 ----
    unsigned short* hw = hB + (size_t)((l * 2 + p) * B_SZ + b) * HROW;
    {
        int w = t >> 2, qd = t & 3;
        unsigned long long u = 0;
        #pragma unroll
        for (int i = 0; i < 4; i++)
            u |= (unsigned long long)bf16_rn(hS[(qd * 4 + i) * 64 + w]) << (16 * i);
        *(unsigned long long*)(hw + (size_t)(w + 2) * 128 + j * 16 + qd * 4) = u;
    }
}

// ---- output projection for one row h ----
__global__ __launch_bounds__(256, 2) void proj_row(
    const float* __restrict__ Wout, const float* __restrict__ bout,
    const float* __restrict__ hf32, float* __restrict__ out, int h)
{
    __shared__ float S[HC * WI];
    const int t  = threadIdx.x;
    const int b  = blockIdx.x / 12;
    const int jo = blockIdx.x % 12;
    const float* hr = hf32 + (size_t)b * CROW;
    for (int c4 = t; c4 < CROW / 4; c4 += 256) ((float4*)S)[c4] = ((const float4*)hr)[c4];
    __syncthreads();

    const int o0 = jo * 64 + (t >> 4) * 4;
    const int w0 = (t & 15) * 4;
    float acc[4][4] = {};
    const float* pw = Wout + (size_t)o0 * HC;
    for (int d = 0; d < HC; d++) {
        float s0 = S[d * 64 + w0 + 0], s1 = S[d * 64 + w0 + 1];
        float s2 = S[d * 64 + w0 + 2], s3 = S[d * 64 + w0 + 3];
        #pragma unroll
        for (int e = 0; e < 4; e++) {
            float wv = pw[e * HC + d];
            acc[e][0] += wv * s0; acc[e][1] += wv * s1;
            acc[e][2] += wv * s2; acc[e][3] += wv * s3;
        }
    }
    #pragma unroll
    for (int e = 0; e < 4; e++) {
        float bb = bout[o0 + e];
        float4 r = { acc[e][0] + bb, acc[e][1] + bb, acc[e][2] + bb, acc[e][3] + bb };
        *(float4*)&out[(((size_t)b * 768 + o0 + e) * 64 + h) * 64 + w0] = r;
    }
}

extern "C" void kernel_launch(void* const* d_in, const int* in_sizes, int n_in,
                              void* d_out, int out_size, void* d_ws, size_t ws_size,
                              hipStream_t stream) {
    const int*   x    = (const int*)  d_in[0];
    const float* Win  = (const float*)d_in[1];
    const float* bin  = (const float*)d_in[2];
    const float* Wx   = (const float*)d_in[3];
    const float* bx   = (const float*)d_in[4];
    const float* Wh   = (const float*)d_in[5];
    const float* Wout = (const float*)d_in[6];
    const float* bout = (const float*)d_in[7];
    float* out = (float*)d_out;

    // ws layout (bytes), total 26,968,064 (< 29.36 MB proven in R1):
    //   hB   @ 0          :  7,569,408  (7*2*32*8448 bf16)
    //   cB   @ 7,569,408  :  7,340,032  (7*32*8192 f32, in-place)
    //   hf32 @ 14,909,440 :  1,048,576  (32*8192 f32)
    //   Apk  @ 15,958,016 : 11,010,048  (688128*8 bf16)
    char* ws = (char*)d_ws;
    unsigned short* hB  = (unsigned short*)ws;
    float*          cB  = (float*)(ws + 7569408);
    float*          hf  = (float*)(ws + 14909440);
    unsigned short* Apk = (unsigned short*)(ws + 15958016);

    hipMemsetAsync(d_ws, 0, 15958016, stream);   // zero h/c states + pads each call
    pack_weights<<<2688, 256, 0, stream>>>(Wx, Wh, Apk);

    for (int h = 0; h < 64; h++) {
        for (int l = 0; l < NL; l++)
            lstm_step<<<256, 256, 0, stream>>>(Apk, bx, x, Win, bin, hB, cB, hf, l, h);
        proj_row<<<384, 256, 0, stream>>>(Wout, bout, hf, out, h);
    }
}

// Round 4
// 4317.442 us; speedup vs baseline: 4.0709x; 1.8725x over previous
//
#include <hip/hip_runtime.h>
#include <cstddef>
#include <cstdint>

// RowLSTM on MFMA, diagonal-wavefront schedule.
// Steps (h,l) with h+l=d are independent -> one kernel per diagonal d=0..70,
// plus folded output-projection for row h=d-7. 71 launches total.
// Per step/batch: comb[512][64] = Wx*cur + Wh*hs, K=768, 32x32x16 bf16 MFMA,
// split-bf16 weights (hi+lo across waves), bf16 states.
//
// Layouts (unchanged from R3 except hf32 gains parity):
//  Apk[l][part][j][ot][kc][lane][8] bf16 ; hB[l][parity][b][66][128] bf16
//  cB[l][b][128][64] f32 in-place ; hf32[parity][b][128][64] f32

#define NL    7
#define HC    128
#define B_SZ  32
#define WI    64
#define HROW  8448   // 66*128
#define CROW  8192   // 128*64

typedef __attribute__((ext_vector_type(8)))  short short8v;
typedef __attribute__((ext_vector_type(16))) float f32x16;
typedef __attribute__((ext_vector_type(4)))  unsigned int uint4v;

__device__ __forceinline__ unsigned short bf16_rn(float f) {
    unsigned int u = __builtin_bit_cast(unsigned int, f);
    u += 0x7fffu + ((u >> 16) & 1u);
    return (unsigned short)(u >> 16);
}
__device__ __forceinline__ float bf16_to_f(unsigned short s) {
    unsigned int u = ((unsigned int)s) << 16;
    return __builtin_bit_cast(float, u);
}
__device__ __forceinline__ float sigmf(float v) { return 1.0f / (1.0f + __expf(-v)); }
__device__ __forceinline__ float tanh_fast(float v) {
    v = fminf(fmaxf(v, -15.0f), 15.0f);
    float e = __expf(2.0f * v);
    return (e - 1.0f) / (e + 1.0f);
}

// ---- pack Wx/Wh into MFMA A-fragment order, split hi/lo bf16 (verified R3) ----
__global__ __launch_bounds__(256) void pack_weights(
    const float* __restrict__ Wx, const float* __restrict__ Wh,
    unsigned short* __restrict__ Apk)
{
    int tid = blockIdx.x * 256 + threadIdx.x;          // 0 .. 688127
    int lane = tid & 63; int tmp = tid >> 6;
    int kc = tmp % 48;   tmp /= 48;
    int ot = tmp & 1;    tmp >>= 1;
    int j  = tmp & 7;    tmp >>= 3;
    int part = tmp & 1;  int l = tmp >> 1;
    int m  = ot * 32 + (lane & 31);
    int oc = (m >> 4) * 128 + j * 16 + (m & 15);
    int k0 = kc * 16 + (lane >> 5) * 8;
    unsigned short v8[8];
    #pragma unroll
    for (int e = 0; e < 8; e++) {
        int K = k0 + e;                                // K = src*384 + ktap*128 + ic
        int src = K / 384; int rr = K - src * 384;
        int ktap = rr >> 7; int ic = rr & 127;
        const float* Wp = src ? Wh : Wx;
        float v = Wp[((size_t)(l * 512 + oc) * 128 + ic) * 3 + ktap];
        unsigned short hi = bf16_rn(v);
        v8[e] = part ? bf16_rn(v - bf16_to_f(hi)) : hi;
    }
    *(uint4v*)(Apk + (size_t)tid * 8) = *(const uint4v*)v8;
}

// ---- one diagonal: step-blocks (2048, idle-trimmed) + proj-blocks (384) ----
__global__ __launch_bounds__(256, 2) void diag_kernel(
    const unsigned short* __restrict__ Apk, const float* __restrict__ bx,
    const int* __restrict__ x, const float* __restrict__ Win, const float* __restrict__ bin,
    unsigned short* __restrict__ hB, float* __restrict__ cB, float* __restrict__ hf32,
    const float* __restrict__ Wout, const float* __restrict__ bout, float* __restrict__ out,
    int d, int h_lo, int nsteps)
{
    __shared__ __align__(16) unsigned char smem[55296];
    const int t = threadIdx.x;
    const unsigned step_region = (nsteps > 0) ? 2048u : 0u;

    if ((unsigned)blockIdx.x >= step_region) {
        // ================= proj role: row hp = d-7 =================
        float* S = (float*)smem;                       // 32 KB
        const int idx = blockIdx.x - step_region;
        const int b = idx / 12, jo = idx % 12;
        const int hp = d - 7;
        const float* hr = hf32 + (size_t)((hp & 1) * B_SZ + b) * CROW;
        for (int c4 = t; c4 < CROW / 4; c4 += 256) ((float4*)S)[c4] = ((const float4*)hr)[c4];
        __syncthreads();
        const int o0 = jo * 64 + (t >> 4) * 4;
        const int w0 = (t & 15) * 4;
        float acc[4][4] = {};
        const float* pw = Wout + (size_t)o0 * HC;
        for (int dd = 0; dd < HC; dd++) {
            float s0 = S[dd * 64 + w0 + 0], s1 = S[dd * 64 + w0 + 1];
            float s2 = S[dd * 64 + w0 + 2], s3 = S[dd * 64 + w0 + 3];
            #pragma unroll
            for (int e = 0; e < 4; e++) {
                float wv = pw[e * HC + dd];
                acc[e][0] += wv * s0; acc[e][1] += wv * s1;
                acc[e][2] += wv * s2; acc[e][3] += wv * s3;
            }
        }
        #pragma unroll
        for (int e = 0; e < 4; e++) {
            float bb = bout[o0 + e];
            float4 r = { acc[e][0] + bb, acc[e][1] + bb, acc[e][2] + bb, acc[e][3] + bb };
            *(float4*)&out[(((size_t)b * 768 + o0 + e) * 64 + hp) * 64 + w0] = r;
        }
        return;
    }

    // ================= lstm step role =================
    const int xs = blockIdx.x & 7;                     // step slot == XCD pin
    if (xs >= nsteps) return;                          // idle (uniform, pre-barrier)
    const int q = blockIdx.x >> 3;                     // 0..255
    const int hh = h_lo + xs, l = d - hh;
    const int b = q & 31, j = q >> 5;
    const int p = hh & 1, pp = p ^ 1;

    unsigned short* Bs    = (unsigned short*)smem;             // 33792 B (cur, hs; XOR-swizzled)
    float*          combS = (float*)(smem + 33792);            // 16384 B
    float*          hS    = (float*)(smem + 50176);            //  4096 B
    float*          bxs   = (float*)(smem + 54272);            //   256 B
    float*          xS    = (float*)(smem + 54528);            //   768 B

    // ---- stage hs (prev row, this layer) ----
    const unsigned short* hsp = hB + (size_t)((l * 2 + pp) * B_SZ + b) * HROW;
    for (int ch = t; ch < 1056; ch += 256) {
        int wr = ch >> 4, icb = ch & 15;
        uint4v v = *(const uint4v*)(hsp + wr * 128 + icb * 8);
        *(uint4v*)((char*)(Bs + HROW) + wr * 256 + ((icb * 16) ^ ((wr & 7) << 4))) = v;
    }
    // ---- stage cur (prev layer this row, or inline input projection) ----
    if (l > 0) {
        const unsigned short* curp = hB + (size_t)(((l - 1) * 2 + p) * B_SZ + b) * HROW;
        for (int ch = t; ch < 1056; ch += 256) {
            int wr = ch >> 4, icb = ch & 15;
            uint4v v = *(const uint4v*)(curp + wr * 128 + icb * 8);
            *(uint4v*)((char*)Bs + wr * 256 + ((icb * 16) ^ ((wr & 7) << 4))) = v;
        }
    } else {
        if (t < 192) xS[t] = (float)x[(size_t)(b * 3 + t / 64) * 4096 + hh * 64 + (t & 63)] * (1.0f / 255.0f);
        {   // zero pad rows 0,1 of cur plane
            int wr = t >> 7, ic = t & 127;
            *(unsigned short*)((char*)Bs + wr * 256 + (((ic >> 3) * 16) ^ ((wr & 7) << 4)) + (ic & 7) * 2) = 0;
        }
        __syncthreads();
        #pragma unroll 4
        for (int e = 0; e < 32; e++) {
            int idx = e * 256 + t; int w = idx >> 7, ic = idx & 127;
            float v = bin[ic] + Win[ic * 3 + 0] * xS[w]
                              + Win[ic * 3 + 1] * xS[64 + w]
                              + Win[ic * 3 + 2] * xS[128 + w];
            int wr = w + 2;
            *(unsigned short*)((char*)Bs + wr * 256 + (((ic >> 3) * 16) ^ ((wr & 7) << 4)) + (ic & 7) * 2) = bf16_rn(v);
        }
    }
    if (t < 64) bxs[t] = bx[l * 512 + (t >> 4) * 128 + j * 16 + (t & 15)];
    __syncthreads();

    // ---- MFMA: 4 waves = (ot: oc-half) x (part: hi/lo); both w-tiles per wave ----
    const int lane = t & 63, wave = t >> 6;
    const int ot = wave >> 1, part = wave & 1;
    const int ln31 = lane & 31, lh = lane >> 5;

    const unsigned short* Ap = Apk + ((((size_t)(l * 2 + part) * 8 + j) * 2 + ot) * 48) * 512 + lane * 8;

    f32x16 acc0, acc1;
    #pragma unroll
    for (int r = 0; r < 16; r++) { acc0[r] = 0.0f; acc1[r] = 0.0f; }

    #pragma unroll
    for (int kc = 0; kc < 48; kc++) {
        const int src  = kc / 24;
        const int ktap = (kc % 24) >> 3;
        const int icb2 = kc & 7;
        const int wr0  = ln31 + ktap;                  // w-tile 0 rows; tile 1 = +32 (same &7)
        const int by   = (icb2 * 32 + lh * 16) ^ ((wr0 & 7) << 4);
        const char* base = (const char*)(Bs + (size_t)src * HROW);
        short8v a   = *(const short8v*)(Ap + kc * 512);
        short8v bv0 = *(const short8v*)(base + wr0 * 256 + by);
        short8v bv1 = *(const short8v*)(base + (wr0 + 32) * 256 + by);
        acc0 = __builtin_amdgcn_mfma_f32_32x32x16_bf16(a, bv0, acc0, 0, 0, 0);
        acc1 = __builtin_amdgcn_mfma_f32_32x32x16_bf16(a, bv1, acc1, 0, 0, 0);
    }

    // ---- combine hi+lo parts through LDS (C/D: col=lane&31, row=(r&3)+8*(r>>2)+4*lh) ----
    if (part == 0) {
        #pragma unroll
        for (int r = 0; r < 16; r++) {
            int row = (r & 3) + 8 * (r >> 2) + 4 * lh;
            combS[(ot * 32 + row) * 64 + ln31]      = acc0[r];
            combS[(ot * 32 + row) * 64 + 32 + ln31] = acc1[r];
        }
    }
    __syncthreads();
    if (part == 1) {
        #pragma unroll
        for (int r = 0; r < 16; r++) {
            int row = (r & 3) + 8 * (r >> 2) + 4 * lh;
            combS[(ot * 32 + row) * 64 + ln31]      += acc0[r];
            combS[(ot * 32 + row) * 64 + 32 + ln31] += acc1[r];
        }
    }
    __syncthreads();

    // ---- gates + in-place c update ----
    float* cp = cB + (size_t)(l * B_SZ + b) * CROW;
    #pragma unroll
    for (int e = 0; e < 4; e++) {
        int idx = e * 256 + t; int dd = idx >> 6, w = idx & 63;
        float gi = combS[(     dd) * 64 + w] + bxs[     dd];
        float gf = combS[(16 + dd) * 64 + w] + bxs[16 + dd];
        float go = combS[(32 + dd) * 64 + w] + bxs[32 + dd];
        float gg = combS[(48 + dd) * 64 + w] + bxs[48 + dd];
        float cold = cp[(j * 16 + dd) * 64 + w];
        float nc = sigmf(gf) * cold + sigmf(gi) * tanh_fast(gg);
        float nh = sigmf(go) * tanh_fast(nc);
        cp[(j * 16 + dd) * 64 + w] = nc;
        hS[dd * 64 + w] = nh;
        if (l == 6) hf32[(size_t)(p * B_SZ + b) * CROW + (j * 16 + dd) * 64 + w] = nh;
    }
    __syncthreads();

    // ---- transposed bf16 h-state write: row w+2, ic = j*16 + 0..15 ----
    unsigned short* hw = hB + (size_t)((l * 2 + p) * B_SZ + b) * HROW;
    {
        int w = t >> 2, qd = t & 3;
        unsigned long long u = 0;
        #pragma unroll
        for (int i = 0; i < 4; i++)
            u |= (unsigned long long)bf16_rn(hS[(qd * 4 + i) * 64 + w]) << (16 * i);
        *(unsigned long long*)(hw + (size_t)(w + 2) * 128 + j * 16 + qd * 4) = u;
    }
}

extern "C" void kernel_launch(void* const* d_in, const int* in_sizes, int n_in,
                              void* d_out, int out_size, void* d_ws, size_t ws_size,
                              hipStream_t stream) {
    const int*   x    = (const int*)  d_in[0];
    const float* Win  = (const float*)d_in[1];
    const float* bin  = (const float*)d_in[2];
    const float* Wx   = (const float*)d_in[3];
    const float* bx   = (const float*)d_in[4];
    const float* Wh   = (const float*)d_in[5];
    const float* Wout = (const float*)d_in[6];
    const float* bout = (const float*)d_in[7];
    float* out = (float*)d_out;

    // ws layout (bytes), total 28,016,640:
    //   hB   @ 0          :  7,569,408  (7*2*32*8448 bf16)
    //   cB   @ 7,569,408  :  7,340,032  (7*32*8192 f32, in-place)
    //   hf32 @ 14,909,440 :  2,097,152  (2 parity * 32 * 8192 f32)
    //   Apk  @ 17,006,592 : 11,010,048  (688128*8 bf16)
    char* ws = (char*)d_ws;
    unsigned short* hB  = (unsigned short*)ws;
    float*          cB  = (float*)(ws + 7569408);
    float*          hf  = (float*)(ws + 14909440);
    unsigned short* Apk = (unsigned short*)(ws + 17006592);

    hipMemsetAsync(d_ws, 0, 17006592, stream);   // zero h/c/hf32 states each call
    pack_weights<<<2688, 256, 0, stream>>>(Wx, Wh, Apk);

    for (int d = 0; d <= 70; d++) {
        int h_lo = (d > 6) ? d - 6 : 0;
        int h_hi = (d < 63) ? d : 63;
        int nsteps = h_hi - h_lo + 1;            // 0 when d == 70
        int grid = ((nsteps > 0) ? 2048 : 0) + ((d >= 7) ? 384 : 0);
        diag_kernel<<<grid, 256, 0, stream>>>(Apk, bx, x, Win, bin, hB, cB, hf,
                                              Wout, bout, out, d, h_lo, nsteps);
    }
}